// Round 2
// baseline (739.307 us; speedup 1.0000x reference)
//
#include <hip/hip_runtime.h>

typedef _Float16 half8 __attribute__((ext_vector_type(8)));
typedef float floatx4 __attribute__((ext_vector_type(4)));

constexpr int U = 8;

// ---- Pass 1: stream-convert fp32 table -> fp16 table in workspace. ----
// Nontemporal loads on the fp32 source so the read-once lines don't evict
// the fp16 destination (which we want resident in the 256 MB Infinity Cache).
__global__ __launch_bounds__(256) void convert_f32_f16(
    const float* __restrict__ emb, _Float16* __restrict__ h, long long n8) {
  long long i = (long long)blockIdx.x * blockDim.x + threadIdx.x;
  long long stride = (long long)gridDim.x * blockDim.x;
  const floatx4* e4 = (const floatx4*)emb;
  half8* h8 = (half8*)h;
  for (long long k = i; k < n8; k += stride) {
    floatx4 x = __builtin_nontemporal_load(&e4[2 * k]);
    floatx4 y = __builtin_nontemporal_load(&e4[2 * k + 1]);
    half8 v;
    v[0] = (_Float16)x[0]; v[1] = (_Float16)x[1];
    v[2] = (_Float16)x[2]; v[3] = (_Float16)x[3];
    v[4] = (_Float16)y[0]; v[5] = (_Float16)y[1];
    v[6] = (_Float16)y[2]; v[7] = (_Float16)y[3];
    h8[k] = v;
  }
}

// ---- Pass 2: gather fp16 rows (256 B each), dot in fp32. ----
// 16-lane groups, 16 B/lane per row, U=8 triplets/group -> 16 vmem ops in
// flight per wave (same MLP as before at half the bytes), 4-shuffle reduce.
__global__ __launch_bounds__(256) void dot_gather_f16(
    const int* __restrict__ trip,       // (T,3) int32
    const _Float16* __restrict__ h,     // (N,128) fp16
    float* __restrict__ out, int T) {
  long long gid = (long long)blockIdx.x * blockDim.x + threadIdx.x;
  long long group = gid >> 4;
  int lane = (int)(gid & 15);
  long long t0 = group * U;
  if (t0 >= T) return;

  int iL[U], iR[U];
  #pragma unroll
  for (int u = 0; u < U; ++u) {
    long long t = (t0 + u < T) ? (t0 + u) : (long long)(T - 1);
    iL[u] = trip[3 * t];
    iR[u] = trip[3 * t + 2];
  }

  half8 a[U], b[U];
  #pragma unroll
  for (int u = 0; u < U; ++u) {
    a[u] = ((const half8*)(h + (long long)iL[u] * 128))[lane];
    b[u] = ((const half8*)(h + (long long)iR[u] * 128))[lane];
  }

  #pragma unroll
  for (int u = 0; u < U; ++u) {
    float s = 0.f;
    #pragma unroll
    for (int j = 0; j < 8; ++j)
      s += (float)a[u][j] * (float)b[u][j];
    #pragma unroll
    for (int off = 8; off > 0; off >>= 1)
      s += __shfl_down(s, off, 16);
    if (lane == 0 && t0 + u < T)
      __builtin_nontemporal_store(s, &out[t0 + u]);
  }
}

// ---- Fallback: previous fp32 direct-gather kernel (used if ws too small). ----
__global__ __launch_bounds__(256) void dot_gather_f32(
    const int* __restrict__ trip, const float* __restrict__ emb,
    float* __restrict__ out, int T) {
  int gid = blockIdx.x * blockDim.x + threadIdx.x;
  int group = gid >> 5;
  int lane = gid & 31;
  long long t0 = (long long)group * U;
  if (t0 >= T) return;
  int iL[U], iR[U];
  #pragma unroll
  for (int u = 0; u < U; ++u) {
    long long t = (t0 + u < T) ? (t0 + u) : (long long)(T - 1);
    iL[u] = trip[3 * t];
    iR[u] = trip[3 * t + 2];
  }
  float4 a[U], b[U];
  #pragma unroll
  for (int u = 0; u < U; ++u) {
    a[u] = ((const float4*)(emb + (long long)iL[u] * 128))[lane];
    b[u] = ((const float4*)(emb + (long long)iR[u] * 128))[lane];
  }
  #pragma unroll
  for (int u = 0; u < U; ++u) {
    float s = a[u].x * b[u].x + a[u].y * b[u].y + a[u].z * b[u].z + a[u].w * b[u].w;
    #pragma unroll
    for (int off = 16; off > 0; off >>= 1)
      s += __shfl_down(s, off, 32);
    if (lane == 0 && t0 + u < T) out[t0 + u] = s;
  }
}

extern "C" void kernel_launch(void* const* d_in, const int* in_sizes, int n_in,
                              void* d_out, int out_size, void* d_ws, size_t ws_size,
                              hipStream_t stream) {
  const int* trip = (const int*)d_in[0];     // triplets (T,3) int32
  const float* emb = (const float*)d_in[1];  // node_emb (N,128) fp32
  float* out = (float*)d_out;

  int T = in_sizes[0] / 3;
  long long nelem = (long long)in_sizes[1];  // N * 128
  size_t need = (size_t)nelem * sizeof(_Float16);

  if (ws_size >= need && (nelem & 7) == 0) {
    _Float16* h = (_Float16*)d_ws;
    long long n8 = nelem / 8;
    convert_f32_f16<<<2048, 256, 0, stream>>>(emb, h, n8);

    long long groups = ((long long)T + U - 1) / U;
    long long total_threads = groups * 16;
    int block = 256;
    long long grid = (total_threads + block - 1) / block;
    dot_gather_f16<<<(int)grid, block, 0, stream>>>(trip, h, out, T);
  } else {
    long long groups = ((long long)T + U - 1) / U;
    long long total_threads = groups * 32;
    int block = 256;
    long long grid = (total_threads + block - 1) / block;
    dot_gather_f32<<<(int)grid, block, 0, stream>>>(trip, emb, out, T);
  }
}

// Round 3
// 699.951 us; speedup vs baseline: 1.0562x; 1.0562x over previous
//
#include <hip/hip_runtime.h>

// Direct fp32 gather: for each triplet t, dot(emb[trip[t,0]], emb[trip[t,2]]).
// 32-lane groups, U=8 triplets/group, float4/lane => each row read is one
// fully-coalesced 512 B transaction; 16 row-gathers in flight per wave.
// No workspace use: the 512 MB table gets ~50% steady-state L3 hits for free
// (mean row multiplicity = 2), and any preprocessing pass costs more
// streaming traffic than it saves (measured round 2: +39 us).
constexpr int U = 8;

__global__ __launch_bounds__(256) void dot_gather_f32(
    const int* __restrict__ trip,   // (T,3) int32
    const float* __restrict__ emb,  // (N,128) fp32
    float* __restrict__ out,        // (T,) fp32
    int T) {
  long long gid = (long long)blockIdx.x * blockDim.x + threadIdx.x;
  long long group = gid >> 5;
  int lane = (int)(gid & 31);
  long long t0 = group * U;
  if (t0 >= T) return;

  // Dedup'd index load: lanes 0..23 fetch the group's 24 trip words once
  // (nontemporal: read-once stream, don't pollute L3), broadcast via shfl.
  // Tail lanes clamp to a valid word; any trip word is a valid node index.
  long long base = 3LL * t0;
  long long tlim = 3LL * T - 1;
  long long idx = base + (lane < 24 ? lane : 0);
  if (idx > tlim) idx = tlim;
  int w = __builtin_nontemporal_load(&trip[idx]);

  int iL[U], iR[U];
  #pragma unroll
  for (int u = 0; u < U; ++u) {
    iL[u] = __shfl(w, 3 * u, 32);
    iR[u] = __shfl(w, 3 * u + 2, 32);
  }

  // Issue all row gathers back-to-back: 16 outstanding 512 B row reads/group.
  float4 a[U], b[U];
  #pragma unroll
  for (int u = 0; u < U; ++u) {
    a[u] = ((const float4*)(emb + (long long)iL[u] * 128))[lane];
    b[u] = ((const float4*)(emb + (long long)iR[u] * 128))[lane];
  }

  // Dot + butterfly reduce; deposit result u into lane u for one coalesced
  // 32 B store per group (instead of 8 serial dword stores from lane 0).
  float r = 0.f;
  #pragma unroll
  for (int u = 0; u < U; ++u) {
    float s = a[u].x * b[u].x + a[u].y * b[u].y +
              a[u].z * b[u].z + a[u].w * b[u].w;
    #pragma unroll
    for (int off = 16; off > 0; off >>= 1)
      s += __shfl_xor(s, off, 32);
    if (lane == u) r = s;
  }
  long long t = t0 + lane;
  if (lane < U && t < T)
    __builtin_nontemporal_store(r, &out[t]);
}

extern "C" void kernel_launch(void* const* d_in, const int* in_sizes, int n_in,
                              void* d_out, int out_size, void* d_ws, size_t ws_size,
                              hipStream_t stream) {
  const int* trip = (const int*)d_in[0];     // triplets (T,3) int32
  const float* emb = (const float*)d_in[1];  // node_emb (N,128) fp32
  float* out = (float*)d_out;

  int T = in_sizes[0] / 3;
  long long groups = ((long long)T + U - 1) / U;
  long long total_threads = groups * 32;
  int block = 256;
  long long grid = (total_threads + block - 1) / block;

  dot_gather_f32<<<(int)grid, block, 0, stream>>>(trip, emb, out, T);
}